// Round 1
// baseline (52.295 us; speedup 1.0000x reference)
//
#include <hip/hip_runtime.h>

#define NDOCS 23
#define FDIM 136
#define H1DIM 128
#define H2DIM 64
#define SIGMA 1.0f

__global__ __launch_bounds__(256) void lambdarank_loss_kernel(
    const float* __restrict__ x,
    const float* __restrict__ W1,
    const float* __restrict__ b1,
    const float* __restrict__ W2,
    const float* __restrict__ b2,
    const float* __restrict__ Wout,
    const float* __restrict__ bout,
    const float* __restrict__ target,
    const int*   __restrict__ docs,
    float* __restrict__ out)
{
    __shared__ int   s_docs[NDOCS];
    __shared__ float s_labels[NDOCS];
    __shared__ float s_x[NDOCS][FDIM];
    __shared__ float s_h1[NDOCS][H1DIM];
    __shared__ float s_h2[NDOCS][H2DIM];
    __shared__ float s_score[NDOCS];
    __shared__ float s_rowL[NDOCS];
    __shared__ float s_rowD[NDOCS];

    const int tid = threadIdx.x;

    // 1. load doc ids + labels
    if (tid < NDOCS) {
        int d = docs[tid];
        s_docs[tid] = d;
        s_labels[tid] = target[d];
    }
    __syncthreads();

    // 2. gather the 23 x rows into LDS
    for (int idx = tid; idx < NDOCS * FDIM; idx += 256) {
        int k = idx / FDIM;
        int f = idx - k * FDIM;
        s_x[k][f] = x[(long long)s_docs[k] * FDIM + f];
    }
    __syncthreads();

    // 3. h1 = relu(x @ W1 + b1)   (23*128 = 2944 outputs)
    for (int idx = tid; idx < NDOCS * H1DIM; idx += 256) {
        int k = idx >> 7;          // / 128
        int j = idx & (H1DIM - 1); // % 128  -> consecutive threads read consecutive W1 cols
        float acc = b1[j];
        #pragma unroll 8
        for (int f = 0; f < FDIM; ++f)
            acc = fmaf(s_x[k][f], W1[f * H1DIM + j], acc);
        s_h1[k][j] = fmaxf(acc, 0.0f);
    }
    __syncthreads();

    // 4. h2 = relu(h1 @ W2 + b2)   (23*64 = 1472 outputs)
    for (int idx = tid; idx < NDOCS * H2DIM; idx += 256) {
        int k = idx >> 6;          // / 64
        int j = idx & (H2DIM - 1); // % 64
        float acc = b2[j];
        #pragma unroll 8
        for (int i = 0; i < H1DIM; ++i)
            acc = fmaf(s_h1[k][i], W2[i * H2DIM + j], acc);
        s_h2[k][j] = fmaxf(acc, 0.0f);
    }
    __syncthreads();

    // 5. scores + per-row lambda/delta sums (lanes 0..22)
    if (tid < NDOCS) {
        float acc = bout[0];
        #pragma unroll 8
        for (int i = 0; i < H2DIM; ++i)
            acc = fmaf(s_h2[tid][i], Wout[i], acc);
        s_score[tid] = acc;

        const float li = s_labels[tid];
        const float wi = 1.0f / (float)(tid + 1);
        const int   di = s_docs[tid];
        float rl = 0.0f, rd = 0.0f;
        for (int j = 0; j < NDOCS; ++j) {
            if (s_docs[j] == di) continue;     // mask on doc IDs (incl. i==j), per reference
            const float lj = s_labels[j];
            const float wj = 1.0f / (float)(j + 1);
            const float dl = li - lj;
            const float S  = (dl > 0.0f) ? 1.0f : ((dl < 0.0f) ? -1.0f : 0.0f);
            rl += SIGMA * (0.5f * (1.0f - S) - 0.5f);
            rd += fabsf((lj - li) * (wi - wj));
        }
        s_rowL[tid] = rl;
        s_rowD[tid] = rd;
    }
    __syncthreads();

    // 6. cumsum + weighted reduction (serial over 23 — negligible)
    if (tid == 0) {
        float cl = 0.0f, cd = 0.0f, loss = 0.0f;
        for (int i = 0; i < NDOCS; ++i) {
            cl += s_rowL[i];
            cd += s_rowD[i];
            loss += cl * cd * s_score[i];
        }
        out[0] = loss;
    }
}

extern "C" void kernel_launch(void* const* d_in, const int* in_sizes, int n_in,
                              void* d_out, int out_size, void* d_ws, size_t ws_size,
                              hipStream_t stream) {
    const float* x      = (const float*)d_in[0];
    const float* W1     = (const float*)d_in[1];
    const float* b1     = (const float*)d_in[2];
    const float* W2     = (const float*)d_in[3];
    const float* b2     = (const float*)d_in[4];
    const float* Wout   = (const float*)d_in[5];
    const float* bout   = (const float*)d_in[6];
    const float* target = (const float*)d_in[7];
    const int*   docs   = (const int*)d_in[8];
    float* out = (float*)d_out;

    hipLaunchKernelGGL(lambdarank_loss_kernel, dim3(1), dim3(256), 0, stream,
                       x, W1, b1, W2, b2, Wout, bout, target, docs, out);
}

// Round 2
// 17.654 us; speedup vs baseline: 2.9621x; 2.9621x over previous
//
#include <hip/hip_runtime.h>

#define NDOCS 23
#define FDIM 136
#define H1DIM 128
#define H2DIM 64
#define SIGMA 1.0f
#define NTHREADS 1024
#define G1 8            // K-split groups for layer 1 (136 = 8*17)
#define F_PER_G 17
#define G2 16           // K-split groups for layer 2 (128 = 16*8)
#define I_PER_G 8
#define XT_PITCH 24     // 23 docs padded to 24 (96B rows, 16B-aligned for float4)
#define H1T_PITCH 24
#define H2_PITCH 68     // 64 + 4 pad to break bank aliasing on step-5 row reads

__global__ __launch_bounds__(NTHREADS) void lambdarank_loss_kernel(
    const float* __restrict__ x,
    const float* __restrict__ W1,
    const float* __restrict__ b1,
    const float* __restrict__ W2,
    const float* __restrict__ b2,
    const float* __restrict__ Wout,
    const float* __restrict__ bout,
    const float* __restrict__ target,
    const int*   __restrict__ docs,
    float* __restrict__ out)
{
    // layer1 partials: 8*23*128 = 23552 floats; layer2: 16*23*64 = 23552. Reused.
    __shared__ float s_part[G1 * NDOCS * H1DIM];          // 94208 B
    __shared__ float s_xT[FDIM * XT_PITCH];               // 13056 B  x^T [f][k]
    __shared__ float s_h1T[H1DIM * H1T_PITCH];            // 12288 B  h1^T [i][k]
    __shared__ float s_h2[NDOCS * H2_PITCH];              //  6256 B  h2 [k][i]
    __shared__ int   s_docs[NDOCS];
    __shared__ float s_labels[NDOCS];
    __shared__ float s_score[NDOCS];
    __shared__ float s_rowL[NDOCS];
    __shared__ float s_rowD[NDOCS];

    const int tid = threadIdx.x;

    // 0. doc ids + labels
    if (tid < NDOCS) {
        int d = docs[tid];
        s_docs[tid] = d;
        s_labels[tid] = target[d];
    }
    __syncthreads();

    // 1. gather the 23 x rows, transposed: s_xT[f][k]
    for (int idx = tid; idx < NDOCS * FDIM; idx += NTHREADS) {
        int k = idx / FDIM;
        int f = idx - k * FDIM;
        s_xT[f * XT_PITCH + k] = x[(long long)s_docs[k] * FDIM + f];
    }
    __syncthreads();

    // 2. layer-1 partials: thread = (j column, f-group g). Each W1 element
    //    loaded exactly once (coalesced over j), 23 FMAs per load.
    {
        const int j = tid & (H1DIM - 1);
        const int g = tid >> 7;
        float acc[NDOCS];
        #pragma unroll
        for (int k = 0; k < NDOCS; ++k) acc[k] = 0.0f;
        const int f0 = g * F_PER_G;
        #pragma unroll
        for (int ff = 0; ff < F_PER_G; ++ff) {
            const int f = f0 + ff;
            const float w = W1[f * H1DIM + j];
            alignas(16) float xv[XT_PITCH];
            #pragma unroll
            for (int q = 0; q < XT_PITCH / 4; ++q)
                *reinterpret_cast<float4*>(&xv[q * 4]) =
                    *reinterpret_cast<const float4*>(&s_xT[f * XT_PITCH + q * 4]);
            #pragma unroll
            for (int k = 0; k < NDOCS; ++k)
                acc[k] = fmaf(xv[k], w, acc[k]);
        }
        #pragma unroll
        for (int k = 0; k < NDOCS; ++k)
            s_part[(g * NDOCS + k) * H1DIM + j] = acc[k];
    }
    __syncthreads();

    // 3. reduce layer-1 partials (fixed g order -> deterministic), bias+relu,
    //    store transposed for layer 2 broadcasts.
    for (int idx = tid; idx < NDOCS * H1DIM; idx += NTHREADS) {
        int k = idx >> 7;
        int j = idx & (H1DIM - 1);
        float a = b1[j];
        #pragma unroll
        for (int g = 0; g < G1; ++g)
            a += s_part[(g * NDOCS + k) * H1DIM + j];
        s_h1T[j * H1T_PITCH + k] = fmaxf(a, 0.0f);
    }
    __syncthreads();

    // 4. layer-2 partials: thread = (j column of 64, i-group g of 16).
    {
        const int j = tid & (H2DIM - 1);
        const int g = tid >> 6;
        float acc[NDOCS];
        #pragma unroll
        for (int k = 0; k < NDOCS; ++k) acc[k] = 0.0f;
        const int i0 = g * I_PER_G;
        #pragma unroll
        for (int ii = 0; ii < I_PER_G; ++ii) {
            const int i = i0 + ii;
            const float w = W2[i * H2DIM + j];
            alignas(16) float hv[H1T_PITCH];
            #pragma unroll
            for (int q = 0; q < H1T_PITCH / 4; ++q)
                *reinterpret_cast<float4*>(&hv[q * 4]) =
                    *reinterpret_cast<const float4*>(&s_h1T[i * H1T_PITCH + q * 4]);
            #pragma unroll
            for (int k = 0; k < NDOCS; ++k)
                acc[k] = fmaf(hv[k], w, acc[k]);
        }
        #pragma unroll
        for (int k = 0; k < NDOCS; ++k)
            s_part[(g * NDOCS + k) * H2DIM + j] = acc[k];
    }
    __syncthreads();

    // 5. reduce layer-2 partials, bias+relu
    for (int idx = tid; idx < NDOCS * H2DIM; idx += NTHREADS) {
        int k = idx >> 6;
        int j = idx & (H2DIM - 1);
        float a = b2[j];
        #pragma unroll
        for (int g = 0; g < G2; ++g)
            a += s_part[(g * NDOCS + k) * H2DIM + j];
        s_h2[k * H2_PITCH + j] = fmaxf(a, 0.0f);
    }
    __syncthreads();

    // 6. scores + per-row lambda/delta sums (lanes 0..22)
    if (tid < NDOCS) {
        float acc = bout[0];
        #pragma unroll 8
        for (int i = 0; i < H2DIM; ++i)
            acc = fmaf(s_h2[tid * H2_PITCH + i], Wout[i], acc);
        s_score[tid] = acc;

        const float li = s_labels[tid];
        const float wi = 1.0f / (float)(tid + 1);
        const int   di = s_docs[tid];
        float rl = 0.0f, rd = 0.0f;
        for (int j = 0; j < NDOCS; ++j) {
            if (s_docs[j] == di) continue;     // mask on doc IDs (incl. i==j), per reference
            const float lj = s_labels[j];
            const float wj = 1.0f / (float)(j + 1);
            const float dl = li - lj;
            const float S  = (dl > 0.0f) ? 1.0f : ((dl < 0.0f) ? -1.0f : 0.0f);
            rl += SIGMA * (0.5f * (1.0f - S) - 0.5f);
            rd += fabsf((lj - li) * (wi - wj));
        }
        s_rowL[tid] = rl;
        s_rowD[tid] = rd;
    }
    __syncthreads();

    // 7. cumsum + weighted reduction (serial over 23 — negligible)
    if (tid == 0) {
        float cl = 0.0f, cd = 0.0f, loss = 0.0f;
        for (int i = 0; i < NDOCS; ++i) {
            cl += s_rowL[i];
            cd += s_rowD[i];
            loss += cl * cd * s_score[i];
        }
        out[0] = loss;
    }
}

extern "C" void kernel_launch(void* const* d_in, const int* in_sizes, int n_in,
                              void* d_out, int out_size, void* d_ws, size_t ws_size,
                              hipStream_t stream) {
    const float* x      = (const float*)d_in[0];
    const float* W1     = (const float*)d_in[1];
    const float* b1     = (const float*)d_in[2];
    const float* W2     = (const float*)d_in[3];
    const float* b2     = (const float*)d_in[4];
    const float* Wout   = (const float*)d_in[5];
    const float* bout   = (const float*)d_in[6];
    const float* target = (const float*)d_in[7];
    const int*   docs   = (const int*)d_in[8];
    float* out = (float*)d_out;

    hipLaunchKernelGGL(lambdarank_loss_kernel, dim3(1), dim3(NTHREADS), 0, stream,
                       x, W1, b1, W2, b2, Wout, bout, target, docs, out);
}

// Round 3
// 17.285 us; speedup vs baseline: 3.0254x; 1.0214x over previous
//
#include <hip/hip_runtime.h>

#define NDOCS 23
#define FDIM 136
#define H1DIM 128
#define H2DIM 64
#define SIGMA 1.0f
#define NTHREADS 1024
#define G1 8            // K-split groups for layer 1 (136 = 8*17)
#define F_PER_G 17
#define G2 16           // K-split groups for layer 2 (128 = 16*8)
#define I_PER_G 8
#define XT_PITCH 24     // 23 docs padded to 24 (96B rows, 16B-aligned for float4)
#define H1T_PITCH 24

__global__ __launch_bounds__(NTHREADS) void lambdarank_loss_kernel(
    const float* __restrict__ x,
    const float* __restrict__ W1,
    const float* __restrict__ b1,
    const float* __restrict__ W2,
    const float* __restrict__ b2,
    const float* __restrict__ Wout,
    const float* __restrict__ bout,
    const float* __restrict__ target,
    const int*   __restrict__ docs,
    float* __restrict__ out)
{
    __shared__ float s_part[G1 * NDOCS * H1DIM];          // 94208 B (reused by layer 2)
    __shared__ float s_xT[FDIM * XT_PITCH];               // 13056 B  x^T [f][k]
    __shared__ float s_h1T[H1DIM * H1T_PITCH];            // 12288 B  h1^T [i][k]
    __shared__ int   s_docs[NDOCS];
    __shared__ float s_labels[NDOCS];
    __shared__ float s_score[NDOCS];
    __shared__ float s_rowL[NDOCS];
    __shared__ float s_rowD[NDOCS];

    const int tid = threadIdx.x;

    // ---- P0: docs load FIRST in the vmcnt FIFO, then weight prefetch.
    //      Waiting on docs (vmcnt(high)) does NOT drain the weight loads,
    //      so the ~100 KB weight fetch overlaps the docs->x latency chain.
    int dd = 0;
    if (tid < 64) dd = docs[tid < NDOCS ? tid : 0];

    const int j1 = tid & (H1DIM - 1);
    const int g1 = tid >> 7;
    float w1r[F_PER_G];
    #pragma unroll
    for (int ff = 0; ff < F_PER_G; ++ff)
        w1r[ff] = W1[(g1 * F_PER_G + ff) * H1DIM + j1];

    const int j2 = tid & (H2DIM - 1);
    const int g2 = tid >> 6;
    float w2r[I_PER_G];
    #pragma unroll
    for (int ii = 0; ii < I_PER_G; ++ii)
        w2r[ii] = W2[(g2 * I_PER_G + ii) * H2DIM + j2];

    const float b1r   = b1[j1];
    const float b2r   = b2[j2];
    const float woutr = Wout[j2];
    const float boutr = bout[0];

    if (tid < NDOCS) s_docs[tid] = dd;     // waits only on the docs load
    __syncthreads();                       // A

    // ---- P1: x gather (q-major: conflict-free transposed LDS stores) + labels
    float lb = 0.0f;
    if (tid < 64) lb = target[dd];
    if (tid < NDOCS * (FDIM / 4)) {        // 23 * 34 = 782 float4 loads
        const int q = tid / NDOCS;
        const int k = tid - q * NDOCS;
        const float4 v = *reinterpret_cast<const float4*>(
            &x[(long long)s_docs[k] * FDIM + q * 4]);
        s_xT[(q * 4 + 0) * XT_PITCH + k] = v.x;
        s_xT[(q * 4 + 1) * XT_PITCH + k] = v.y;
        s_xT[(q * 4 + 2) * XT_PITCH + k] = v.z;
        s_xT[(q * 4 + 3) * XT_PITCH + k] = v.w;
    }
    if (tid < NDOCS) s_labels[tid] = lb;
    __syncthreads();                       // B

    // ---- P2: layer-1 partials: thread = (j1, g1). W in regs, x broadcast b128.
    {
        float acc[NDOCS];
        #pragma unroll
        for (int k = 0; k < NDOCS; ++k) acc[k] = 0.0f;
        #pragma unroll
        for (int ff = 0; ff < F_PER_G; ++ff) {
            const int f = g1 * F_PER_G + ff;
            alignas(16) float xv[XT_PITCH];
            #pragma unroll
            for (int q = 0; q < XT_PITCH / 4; ++q)
                *reinterpret_cast<float4*>(&xv[q * 4]) =
                    *reinterpret_cast<const float4*>(&s_xT[f * XT_PITCH + q * 4]);
            #pragma unroll
            for (int k = 0; k < NDOCS; ++k)
                acc[k] = fmaf(xv[k], w1r[ff], acc[k]);
        }
        #pragma unroll
        for (int k = 0; k < NDOCS; ++k)
            s_part[(g1 * NDOCS + k) * H1DIM + j1] = acc[k];
    }
    __syncthreads();                       // C

    // ---- P3: reduce layer-1 partials (fixed g order), bias+relu, transpose
    #pragma unroll
    for (int m = 0; m < 3; ++m) {
        const int idx = tid + m * NTHREADS;
        if (idx < NDOCS * H1DIM) {
            const int k = idx >> 7;
            const int j = idx & (H1DIM - 1);   // == j1
            float a = b1r;
            #pragma unroll
            for (int g = 0; g < G1; ++g)
                a += s_part[(g * NDOCS + k) * H1DIM + j];
            s_h1T[j * H1T_PITCH + k] = fmaxf(a, 0.0f);
        }
    }
    __syncthreads();                       // D

    // ---- P4: layer-2 partials: thread = (j2, g2)
    {
        float acc[NDOCS];
        #pragma unroll
        for (int k = 0; k < NDOCS; ++k) acc[k] = 0.0f;
        #pragma unroll
        for (int ii = 0; ii < I_PER_G; ++ii) {
            const int i = g2 * I_PER_G + ii;
            alignas(16) float hv[H1T_PITCH];
            #pragma unroll
            for (int q = 0; q < H1T_PITCH / 4; ++q)
                *reinterpret_cast<float4*>(&hv[q * 4]) =
                    *reinterpret_cast<const float4*>(&s_h1T[i * H1T_PITCH + q * 4]);
            #pragma unroll
            for (int k = 0; k < NDOCS; ++k)
                acc[k] = fmaf(hv[k], w2r[ii], acc[k]);
        }
        #pragma unroll
        for (int k = 0; k < NDOCS; ++k)
            s_part[(g2 * NDOCS + k) * H2DIM + j2] = acc[k];
    }
    __syncthreads();                       // E

    // ---- P5: fused reduce-2 + relu + Wout dot (wave-per-doc shuffle tree),
    //          plus lambda/delta row sums in wave 8's spare slot.
    #pragma unroll
    for (int m = 0; m < 2; ++m) {
        const int idx = tid + m * NTHREADS;
        float c = 0.0f;
        if (idx < NDOCS * H2DIM) {
            const int k = idx >> 6;
            const int i = idx & (H2DIM - 1);   // == j2
            float a = b2r;
            #pragma unroll
            for (int g = 0; g < G2; ++g)
                a += s_part[(g * NDOCS + k) * H2DIM + i];
            c = fmaxf(a, 0.0f) * woutr;        // woutr == Wout[i]
        }
        #pragma unroll
        for (int off = 32; off > 0; off >>= 1)
            c += __shfl_down(c, off, 64);
        if ((tid & 63) == 0 && idx < NDOCS * H2DIM)
            s_score[idx >> 6] = c + boutr;
    }

    if (tid >= 512 && tid < 512 + NDOCS) {     // wave 8: pairwise row sums
        const int i  = tid - 512;
        const float li = s_labels[i];
        const float wi = 1.0f / (float)(i + 1);
        const int   di = s_docs[i];
        float rl = 0.0f, rd = 0.0f;
        for (int j = 0; j < NDOCS; ++j) {
            if (s_docs[j] == di) continue;     // mask on doc IDs, per reference bug
            const float lj = s_labels[j];
            const float wj = 1.0f / (float)(j + 1);
            const float dl = li - lj;
            const float S  = (dl > 0.0f) ? 1.0f : ((dl < 0.0f) ? -1.0f : 0.0f);
            rl += SIGMA * (0.5f * (1.0f - S) - 0.5f);
            rd += fabsf((lj - li) * (wi - wj));
        }
        s_rowL[i] = rl;
        s_rowD[i] = rd;
    }
    __syncthreads();                       // F

    // ---- P6: cumsum + weighted reduction (serial over 23 — negligible)
    if (tid == 0) {
        float cl = 0.0f, cd = 0.0f, loss = 0.0f;
        for (int i = 0; i < NDOCS; ++i) {
            cl += s_rowL[i];
            cd += s_rowD[i];
            loss += cl * cd * s_score[i];
        }
        out[0] = loss;
    }
}

extern "C" void kernel_launch(void* const* d_in, const int* in_sizes, int n_in,
                              void* d_out, int out_size, void* d_ws, size_t ws_size,
                              hipStream_t stream) {
    const float* x      = (const float*)d_in[0];
    const float* W1     = (const float*)d_in[1];
    const float* b1     = (const float*)d_in[2];
    const float* W2     = (const float*)d_in[3];
    const float* b2     = (const float*)d_in[4];
    const float* Wout   = (const float*)d_in[5];
    const float* bout   = (const float*)d_in[6];
    const float* target = (const float*)d_in[7];
    const int*   docs   = (const int*)d_in[8];
    float* out = (float*)d_out;

    hipLaunchKernelGGL(lambdarank_loss_kernel, dim3(1), dim3(NTHREADS), 0, stream,
                       x, W1, b1, W2, b2, Wout, bout, target, docs, out);
}

// Round 4
// 15.445 us; speedup vs baseline: 3.3860x; 1.1192x over previous
//
#include <hip/hip_runtime.h>

#define NDOCS 23
#define FDIM 136
#define H1DIM 128
#define H2DIM 64
#define SIGMA 1.0f
#define NT 512
#define G1 8            // layer-1 K-split groups (136 = 8*17)
#define FPG 17
#define G2 8            // layer-2 K-split groups (128 = 8*16)
#define IPG 16
#define XT_PITCH 24     // 23 padded to 24 (96B rows, 16B-aligned)
#define H1T_PITCH 28    // 28 floats = 112B: 16B-aligned, 8-way (not 16-way) write conflict

__global__ __launch_bounds__(NT, 2) void lambdarank_loss_kernel(
    const float* __restrict__ x,
    const float* __restrict__ W1,
    const float* __restrict__ b1,
    const float* __restrict__ W2,
    const float* __restrict__ b2,
    const float* __restrict__ Wout,
    const float* __restrict__ bout,
    const float* __restrict__ target,
    const int*   __restrict__ docs,
    float* __restrict__ out)
{
    __shared__ float s_part[G1 * NDOCS * H1DIM];   // 94208 B (reused by layer 2)
    __shared__ float s_xT[FDIM * XT_PITCH];        // 13056 B  x^T [f][k]
    __shared__ float s_h1T[H1DIM * H1T_PITCH];     // 14336 B  h1^T [i][k]
    __shared__ float s_score[NDOCS];
    __shared__ float s_rowL[NDOCS];
    __shared__ float s_rowD[NDOCS];

    const int tid  = threadIdx.x;
    const int lane = tid & 63;
    const int wv   = tid >> 6;      // 0..7

    // ---- P0: docs first in the VMEM FIFO, then the full weight prefetch.
    //      docs[k] is broadcast via __shfl (register bpermute) -> NO barrier
    //      between docs and the x-gather, so the ~100 KB weight fetch truly
    //      overlaps the docs->x dependent-latency chain (first drain is
    //      barrier B, after the gather).
    int dd = docs[lane < NDOCS ? lane : 0];     // every wave loads (same cacheline)

    float w1a[FPG], w1b[FPG];
    #pragma unroll
    for (int ff = 0; ff < FPG; ++ff) {
        w1a[ff] = W1[(wv * FPG + ff) * H1DIM + lane];
        w1b[ff] = W1[(wv * FPG + ff) * H1DIM + lane + 64];
    }
    float w2r[IPG];
    #pragma unroll
    for (int ii = 0; ii < IPG; ++ii)
        w2r[ii] = W2[(wv * IPG + ii) * H2DIM + lane];
    const float b1a   = b1[lane];
    const float b1b   = b1[lane + 64];
    const float b2r   = b2[lane];
    const float woutr = Wout[lane];
    const float boutr = bout[0];

    float lb = 0.0f;
    if (wv == 7 && lane < NDOCS) lb = target[dd];   // labels live in wave 7 regs

    // ---- P1: x gather, q-major (conflict-free transposed LDS stores).
    //      shfl hoisted OUT of the guard so all 64 source lanes are active.
    #pragma unroll
    for (int m = 0; m < 2; ++m) {
        const int idx = tid + m * NT;
        const int q   = idx / NDOCS;
        const int kk  = idx - q * NDOCS;
        const int dk  = __shfl(dd, kk, 64);
        if (idx < NDOCS * (FDIM / 4)) {             // 782 float4 loads
            const float4 v = *reinterpret_cast<const float4*>(
                &x[(long long)dk * FDIM + q * 4]);
            s_xT[(q * 4 + 0) * XT_PITCH + kk] = v.x;
            s_xT[(q * 4 + 1) * XT_PITCH + kk] = v.y;
            s_xT[(q * 4 + 2) * XT_PITCH + kk] = v.z;
            s_xT[(q * 4 + 3) * XT_PITCH + kk] = v.w;
        }
    }
    __syncthreads();                                // B (single drain point)

    // ---- P2: layer-1 partials, j-pair: thread = (lane -> cols {lane, lane+64},
    //      wv -> f-group). 46 FMA per 6 broadcast b128 reads; LDS instrs halved.
    {
        float accA[NDOCS], accB[NDOCS];
        #pragma unroll
        for (int k = 0; k < NDOCS; ++k) { accA[k] = 0.0f; accB[k] = 0.0f; }
        #pragma unroll
        for (int ff = 0; ff < FPG; ++ff) {
            const float* xr = &s_xT[(wv * FPG + ff) * XT_PITCH];
            alignas(16) float xv[XT_PITCH];
            #pragma unroll
            for (int q = 0; q < XT_PITCH / 4; ++q)
                *reinterpret_cast<float4*>(&xv[q * 4]) =
                    *reinterpret_cast<const float4*>(&xr[q * 4]);
            #pragma unroll
            for (int k = 0; k < NDOCS; ++k) {
                accA[k] = fmaf(xv[k], w1a[ff], accA[k]);
                accB[k] = fmaf(xv[k], w1b[ff], accB[k]);
            }
        }
        #pragma unroll
        for (int k = 0; k < NDOCS; ++k) {
            s_part[(wv * NDOCS + k) * H1DIM + lane]      = accA[k];
            s_part[(wv * NDOCS + k) * H1DIM + lane + 64] = accB[k];
        }
    }
    __syncthreads();                                // C

    // ---- P3: reduce layer-1 partials (fixed g order), bias+relu, transpose
    #pragma unroll
    for (int m = 0; m < 6; ++m) {
        const int k = wv + 8 * (m >> 1);
        const int j = lane + 64 * (m & 1);
        if (k < NDOCS) {
            float a = (m & 1) ? b1b : b1a;
            #pragma unroll
            for (int g = 0; g < G1; ++g)
                a += s_part[(g * NDOCS + k) * H1DIM + j];
            s_h1T[j * H1T_PITCH + k] = fmaxf(a, 0.0f);
        }
    }
    __syncthreads();                                // D

    // ---- P4: layer-2 partials: thread = (lane -> col j2, wv -> i-group of 16)
    {
        float acc[NDOCS];
        #pragma unroll
        for (int k = 0; k < NDOCS; ++k) acc[k] = 0.0f;
        #pragma unroll
        for (int ii = 0; ii < IPG; ++ii) {
            const float* hr = &s_h1T[(wv * IPG + ii) * H1T_PITCH];
            alignas(16) float hv[24];
            #pragma unroll
            for (int q = 0; q < 6; ++q)
                *reinterpret_cast<float4*>(&hv[q * 4]) =
                    *reinterpret_cast<const float4*>(&hr[q * 4]);
            #pragma unroll
            for (int k = 0; k < NDOCS; ++k)
                acc[k] = fmaf(hv[k], w2r[ii], acc[k]);
        }
        #pragma unroll
        for (int k = 0; k < NDOCS; ++k)
            s_part[(wv * NDOCS + k) * H2DIM + lane] = acc[k];
    }
    __syncthreads();                                // E

    // ---- P5: fused reduce-2 + relu + Wout dot (wave-per-doc shuffle tree)
    #pragma unroll
    for (int m = 0; m < 3; ++m) {
        const int idx = tid + m * NT;
        float c = 0.0f;
        if (idx < NDOCS * H2DIM) {
            const int k = idx >> 6;                 // doc
            float a = b2r;                          // i == lane
            #pragma unroll
            for (int g = 0; g < G2; ++g)
                a += s_part[(g * NDOCS + k) * H2DIM + lane];
            c = fmaxf(a, 0.0f) * woutr;             // woutr == Wout[lane]
        }
        #pragma unroll
        for (int off = 32; off > 0; off >>= 1)
            c += __shfl_down(c, off, 64);
        if (lane == 0 && idx < NDOCS * H2DIM)
            s_score[idx >> 6] = c + boutr;
    }

    // wave 7: pairwise lambda/delta row sums, all from registers via shfl
    if (wv == 7 && lane < NDOCS) {
        const float li = lb;
        const float wi = 1.0f / (float)(lane + 1);
        const int   di = dd;
        float rl = 0.0f, rd = 0.0f;
        for (int j = 0; j < NDOCS; ++j) {
            const int   dj = __shfl(dd, j, 64);
            const float lj = __shfl(lb, j, 64);
            if (dj == di) continue;                 // mask on doc IDs, per reference bug
            const float wj = 1.0f / (float)(j + 1);
            const float dl = li - lj;
            const float S  = (dl > 0.0f) ? 1.0f : ((dl < 0.0f) ? -1.0f : 0.0f);
            rl += SIGMA * (0.5f * (1.0f - S) - 0.5f);
            rd += fabsf((lj - li) * (wi - wj));
        }
        s_rowL[lane] = rl;
        s_rowD[lane] = rd;
    }
    __syncthreads();                                // F

    // ---- P6: cumsum + weighted reduction (serial over 23 — negligible)
    if (tid == 0) {
        float cl = 0.0f, cd = 0.0f, loss = 0.0f;
        for (int i = 0; i < NDOCS; ++i) {
            cl += s_rowL[i];
            cd += s_rowD[i];
            loss += cl * cd * s_score[i];
        }
        out[0] = loss;
    }
}

extern "C" void kernel_launch(void* const* d_in, const int* in_sizes, int n_in,
                              void* d_out, int out_size, void* d_ws, size_t ws_size,
                              hipStream_t stream) {
    const float* x      = (const float*)d_in[0];
    const float* W1     = (const float*)d_in[1];
    const float* b1     = (const float*)d_in[2];
    const float* W2     = (const float*)d_in[3];
    const float* b2     = (const float*)d_in[4];
    const float* Wout   = (const float*)d_in[5];
    const float* bout   = (const float*)d_in[6];
    const float* target = (const float*)d_in[7];
    const int*   docs   = (const int*)d_in[8];
    float* outp = (float*)d_out;

    hipLaunchKernelGGL(lambdarank_loss_kernel, dim3(1), dim3(NT), 0, stream,
                       x, W1, b1, W2, b2, Wout, bout, target, docs, outp);
}

// Round 5
// 15.220 us; speedup vs baseline: 3.4358x; 1.0147x over previous
//
#include <hip/hip_runtime.h>

#define NDOCS 23
#define FDIM 136
#define H1DIM 128
#define H2DIM 64
#define SIGMA 1.0f
#define NT 512
#define G1 8            // layer-1 K-split groups (136 = 8*17)
#define FPG 17
#define G2 8            // layer-2 K-split groups (128 = 8*16)
#define IPG 16
#define XT_PITCH 24     // 23 padded to 24 (96B rows, 16B-aligned)
#define H1T_PITCH 28    // 112B rows: 16B-aligned, pad slots zeroed

typedef float f2 __attribute__((ext_vector_type(2)));

__global__ __launch_bounds__(NT, 2) void lambdarank_loss_kernel(
    const float* __restrict__ x,
    const float* __restrict__ W1,
    const float* __restrict__ b1,
    const float* __restrict__ W2,
    const float* __restrict__ b2,
    const float* __restrict__ Wout,
    const float* __restrict__ bout,
    const float* __restrict__ target,
    const int*   __restrict__ docs,
    float* __restrict__ out)
{
    __shared__ float s_part[G1 * NDOCS * H1DIM];   // 94208 B (reused by layer 2)
    __shared__ float s_xT[FDIM * XT_PITCH];        // 13056 B  x^T [f][k]
    __shared__ float s_h1T[H1DIM * H1T_PITCH];     // 14336 B  h1^T [i][k]
    __shared__ float s_score[NDOCS];
    __shared__ float s_rowL[NDOCS];
    __shared__ float s_rowD[NDOCS];

    const int tid  = threadIdx.x;
    const int lane = tid & 63;
    const int wv   = tid >> 6;      // 0..7

    // ---- P0: docs first in the VMEM FIFO, then the full weight prefetch.
    //      docs[k] broadcast via __shfl -> no barrier between docs and the
    //      x-gather; the ~100 KB weight fetch overlaps the docs->x chain.
    int dd = docs[lane < NDOCS ? lane : 0];

    float w1a[FPG], w1b[FPG];
    #pragma unroll
    for (int ff = 0; ff < FPG; ++ff) {
        w1a[ff] = W1[(wv * FPG + ff) * H1DIM + lane];
        w1b[ff] = W1[(wv * FPG + ff) * H1DIM + lane + 64];
    }
    float w2r[IPG];
    #pragma unroll
    for (int ii = 0; ii < IPG; ++ii)
        w2r[ii] = W2[(wv * IPG + ii) * H2DIM + lane];
    const float b1a   = b1[lane];
    const float b1b   = b1[lane + 64];
    const float b2r   = b2[lane];
    const float woutr = Wout[lane];
    const float boutr = bout[0];

    float lb = 0.0f;
    if (wv == 7 && lane < NDOCS) lb = target[dd];   // labels in wave-7 regs

    // ---- P1: x gather, q-major (conflict-free transposed LDS stores)
    #pragma unroll
    for (int m = 0; m < 2; ++m) {
        const int idx = tid + m * NT;
        const int q   = idx / NDOCS;
        const int kk  = idx - q * NDOCS;
        const int dk  = __shfl(dd, kk, 64);
        if (idx < NDOCS * (FDIM / 4)) {             // 782 float4 loads
            const float4 v = *reinterpret_cast<const float4*>(
                &x[(long long)dk * FDIM + q * 4]);
            s_xT[(q * 4 + 0) * XT_PITCH + kk] = v.x;
            s_xT[(q * 4 + 1) * XT_PITCH + kk] = v.y;
            s_xT[(q * 4 + 2) * XT_PITCH + kk] = v.z;
            s_xT[(q * 4 + 3) * XT_PITCH + kk] = v.w;
        }
    }
    if (tid < FDIM) s_xT[tid * XT_PITCH + NDOCS] = 0.0f;  // zero pad slot k=23
    __syncthreads();                                // B (single drain point)

    // ---- P2: layer-1 partials, j-pair, packed fp32 (v_pk_fma_f32):
    //      thread = (lane -> cols {lane, lane+64}, wv -> f-group)
    {
        alignas(16) float accA[XT_PITCH], accB[XT_PITCH];
        f2* a2 = reinterpret_cast<f2*>(accA);
        f2* bb2 = reinterpret_cast<f2*>(accB);
        #pragma unroll
        for (int q = 0; q < XT_PITCH / 2; ++q) { a2[q] = (f2)0.0f; bb2[q] = (f2)0.0f; }
        #pragma unroll
        for (int ff = 0; ff < FPG; ++ff) {
            const float* xr = &s_xT[(wv * FPG + ff) * XT_PITCH];
            alignas(16) float xv[XT_PITCH];
            #pragma unroll
            for (int q = 0; q < XT_PITCH / 4; ++q)
                *reinterpret_cast<float4*>(&xv[q * 4]) =
                    *reinterpret_cast<const float4*>(&xr[q * 4]);
            const f2* x2 = reinterpret_cast<const f2*>(xv);
            const f2 wa2 = {w1a[ff], w1a[ff]};
            const f2 wb2 = {w1b[ff], w1b[ff]};
            #pragma unroll
            for (int q = 0; q < XT_PITCH / 2; ++q) {
                a2[q]  = __builtin_elementwise_fma(x2[q], wa2, a2[q]);
                bb2[q] = __builtin_elementwise_fma(x2[q], wb2, bb2[q]);
            }
        }
        #pragma unroll
        for (int k = 0; k < NDOCS; ++k) {
            s_part[(wv * NDOCS + k) * H1DIM + lane]      = accA[k];
            s_part[(wv * NDOCS + k) * H1DIM + lane + 64] = accB[k];
        }
    }
    __syncthreads();                                // C

    // ---- P3: reduce layer-1 partials (fixed g order), bias+relu, transpose
    #pragma unroll
    for (int m = 0; m < 6; ++m) {
        const int k = wv + 8 * (m >> 1);
        const int j = lane + 64 * (m & 1);
        if (k < NDOCS) {
            float a = (m & 1) ? b1b : b1a;
            #pragma unroll
            for (int g = 0; g < G1; ++g)
                a += s_part[(g * NDOCS + k) * H1DIM + j];
            s_h1T[j * H1T_PITCH + k] = fmaxf(a, 0.0f);
        }
    }
    if (tid < H1DIM) s_h1T[tid * H1T_PITCH + NDOCS] = 0.0f;  // zero pad slot k=23
    __syncthreads();                                // D

    // ---- P4: layer-2 partials, packed fp32: thread = (lane -> col, wv -> i-group)
    {
        alignas(16) float acc[24];
        f2* a2 = reinterpret_cast<f2*>(acc);
        #pragma unroll
        for (int q = 0; q < 12; ++q) a2[q] = (f2)0.0f;
        #pragma unroll
        for (int ii = 0; ii < IPG; ++ii) {
            const float* hr = &s_h1T[(wv * IPG + ii) * H1T_PITCH];
            alignas(16) float hv[24];
            #pragma unroll
            for (int q = 0; q < 6; ++q)
                *reinterpret_cast<float4*>(&hv[q * 4]) =
                    *reinterpret_cast<const float4*>(&hr[q * 4]);
            const f2* h2v = reinterpret_cast<const f2*>(hv);
            const f2 w2 = {w2r[ii], w2r[ii]};
            #pragma unroll
            for (int q = 0; q < 12; ++q)
                a2[q] = __builtin_elementwise_fma(h2v[q], w2, a2[q]);
        }
        #pragma unroll
        for (int k = 0; k < NDOCS; ++k)
            s_part[(wv * NDOCS + k) * H2DIM + lane] = acc[k];
    }
    __syncthreads();                                // E

    // ---- P5: fused reduce-2 + relu + Wout dot (wave-per-doc shuffle tree)
    #pragma unroll
    for (int m = 0; m < 3; ++m) {
        const int idx = tid + m * NT;
        float c = 0.0f;
        if (idx < NDOCS * H2DIM) {
            const int k = idx >> 6;                 // doc
            float a = b2r;                          // i == lane
            #pragma unroll
            for (int g = 0; g < G2; ++g)
                a += s_part[(g * NDOCS + k) * H2DIM + lane];
            c = fmaxf(a, 0.0f) * woutr;             // woutr == Wout[lane]
        }
        #pragma unroll
        for (int off = 32; off > 0; off >>= 1)
            c += __shfl_down(c, off, 64);
        if (lane == 0 && idx < NDOCS * H2DIM)
            s_score[idx >> 6] = c + boutr;
    }

    // wave 7: pairwise lambda/delta row sums, all from registers via shfl
    if (wv == 7 && lane < NDOCS) {
        const float li = lb;
        const float wi = 1.0f / (float)(lane + 1);
        const int   di = dd;
        float rl = 0.0f, rd = 0.0f;
        for (int j = 0; j < NDOCS; ++j) {
            const int   dj = __shfl(dd, j, 64);
            const float lj = __shfl(lb, j, 64);
            if (dj == di) continue;                 // mask on doc IDs, per reference bug
            const float wj = 1.0f / (float)(j + 1);
            const float dl = li - lj;
            const float S  = (dl > 0.0f) ? 1.0f : ((dl < 0.0f) ? -1.0f : 0.0f);
            rl += SIGMA * (0.5f * (1.0f - S) - 0.5f);
            rd += fabsf((lj - li) * (wi - wj));
        }
        s_rowL[lane] = rl;
        s_rowD[lane] = rd;
    }
    __syncthreads();                                // F

    // ---- P6: cumsum via wave-0 shuffle prefix + dot via shuffle tree
    if (wv == 0) {
        float rl = (lane < NDOCS) ? s_rowL[lane]  : 0.0f;
        float rd = (lane < NDOCS) ? s_rowD[lane]  : 0.0f;
        float sc = (lane < NDOCS) ? s_score[lane] : 0.0f;
        float cl = rl, cd = rd;
        #pragma unroll
        for (int off = 1; off < 32; off <<= 1) {
            const float tl = __shfl_up(cl, off, 64);
            const float td = __shfl_up(cd, off, 64);
            if (lane >= off) { cl += tl; cd += td; }
        }
        float v = (lane < NDOCS) ? cl * cd * sc : 0.0f;
        #pragma unroll
        for (int off = 32; off > 0; off >>= 1)
            v += __shfl_down(v, off, 64);
        if (lane == 0) out[0] = v;
    }
}

extern "C" void kernel_launch(void* const* d_in, const int* in_sizes, int n_in,
                              void* d_out, int out_size, void* d_ws, size_t ws_size,
                              hipStream_t stream) {
    const float* x      = (const float*)d_in[0];
    const float* W1     = (const float*)d_in[1];
    const float* b1     = (const float*)d_in[2];
    const float* W2     = (const float*)d_in[3];
    const float* b2     = (const float*)d_in[4];
    const float* Wout   = (const float*)d_in[5];
    const float* bout   = (const float*)d_in[6];
    const float* target = (const float*)d_in[7];
    const int*   docs   = (const int*)d_in[8];
    float* outp = (float*)d_out;

    hipLaunchKernelGGL(lambdarank_loss_kernel, dim3(1), dim3(NT), 0, stream,
                       x, W1, b1, W2, b2, Wout, bout, target, docs, outp);
}